// Round 1
// baseline (9227.055 us; speedup 1.0000x reference)
//
#include <hip/hip_runtime.h>

// Decoder_8014408974552 R5: de-serialize the phase machine.
// R4 was barrier-bound: 50 vmcnt(0)+barrier points per timestep with ONE
// lock-stepped block/CU (hn = 100 KB LDS forced LDS_Block_Size 151552 ->
// 1 block/CU) and single 24-long dependent MFMA chains in the gh phases.
// R5: (1) hn deleted -- old h lives in hold[24] regs, new h accumulates in
// hnew[24] regs, C<->A transposes via a 2.5 KB/wave scratch (chunk loop fully
// unrolled so all register indices are CONSTANT -- no scratch demotion);
// (2) blocks shrink to 2 waves / 64 rows -> 512 blocks, LDS 79872 B ->
// 2 independent blocks/CU whose barrier tails overlap; (3) gh split 3->2
// phases (ghA = r/z/n kf0..11, ghB = kf12..23): 38 barriers/t instead of 50,
// and 3 interleaved accumulator chains per phase instead of 1x24.

#define TT   30
#define SS   40      // scr row stride in u16 (80 B = 20 dwords, 20 % 8 == 4 -> conflict-free b128)
#define CHU  49152   // u16 per chunk (gi 24KB + ghA 36KB + ghB 36KB)
#define GI_U 12288   // gi phase size in u16   (24 KB, 24 frags)
#define GH_U 18432   // gh half-phase in u16   (36 KB, 36 frags)
#define D0_U 589824  // Wd1 tile 0 base (u16)
#define D1_U 602112  // Wd1 tile 1 base (u16)

typedef unsigned short u16;
typedef __bf16 bf16x8 __attribute__((ext_vector_type(8)));
typedef u16    u16x8  __attribute__((ext_vector_type(8)));
typedef float  f32x16 __attribute__((ext_vector_type(16)));

__device__ __forceinline__ u16 f2b(float f){           // fp32 -> bf16 RNE
  unsigned u = __float_as_uint(f);
  u += 0x7FFFu + ((u >> 16) & 1u);
  return (u16)(u >> 16);
}
__device__ __forceinline__ float b2f(u16 h){ return __uint_as_float(((unsigned)h) << 16); }

__device__ __forceinline__ f32x16 mfma32(u16x8 a, u16x8 b, f32x16 c){
  return __builtin_amdgcn_mfma_f32_32x32x16_bf16(
      __builtin_bit_cast(bf16x8, a), __builtin_bit_cast(bf16x8, b), c, 0, 0, 0);
}
__device__ __forceinline__ void lds_fence(){ asm volatile("s_waitcnt lgkmcnt(0)" ::: "memory"); }
__device__ __forceinline__ void vm_fence(){ asm volatile("s_waitcnt vmcnt(0)" ::: "memory"); }
__device__ __forceinline__ float sigf(float x){ return __builtin_amdgcn_rcpf(1.f + __expf(-x)); }
__device__ __forceinline__ float tanh_(float x){ return 2.f*__builtin_amdgcn_rcpf(1.f + __expf(-2.f*x)) - 1.f; }

__device__ __forceinline__ void stage16(const u16* g, u16* l){
  __builtin_amdgcn_global_load_lds(
      (const __attribute__((address_space(1))) unsigned int*)g,
      (__attribute__((address_space(3))) unsigned int*)l, 16, 0, 0);
}

// ---------------------------------------------------------------- prep ----
// Stream layout per chunk c (c = 0..11), base = c*CHU:
//   +0      : gi  [gi_r kf0..7][gi_z kf0..7][gi_n kf0..7]      (24 frags)
//   +GI_U   : ghA [gh_r kf0..11][gh_z kf0..11][gh_n kf0..11]   (36 frags)
//   +GI_U+GH_U : ghB same with kf12..23                         (36 frags)
// then D0_U: Wd1 tile0 kf0..23, D1_U: Wd1 tile1 kf0..23.
// frag: u16 idx (lane&31 + 32*(lane>>5))*8 + j -> B[k][n], n=c*32+(lane&31),
// k = kf*16 + (lane>>5)*8 + j
__global__ void prep_kernel(const float* __restrict__ Wih, const float* __restrict__ Whh,
                            const float* __restrict__ Wd1, const float* __restrict__ Wd2,
                            const float* __restrict__ bih, const float* __restrict__ bhh,
                            const float* __restrict__ Ws,  const float* __restrict__ bs,
                            const float* __restrict__ Wp,  const float* __restrict__ bp,
                            u16* __restrict__ stream, u16* __restrict__ wd2p,
                            u16* __restrict__ wxp, float* __restrict__ gb)
{
  int i = blockIdx.x*blockDim.x + threadIdx.x;
  if (i < 442368){  // W_hh [1152][384] -> ghA/ghB
    int row = i/384, k = i - row*384;
    int g = row/384, unit = row - g*384, c = unit>>5, lc = unit&31;
    int kf = k>>4, hl = (k>>3)&1, j = k&7;
    size_t off = (size_t)c*CHU
               + (kf < 12 ? (size_t)GI_U        + (size_t)(g*12 + kf     )*512
                          : (size_t)(GI_U+GH_U) + (size_t)(g*12 + (kf-12))*512);
    stream[off + (lc+32*hl)*8 + j] = f2b(Whh[i]);
  }
  if (i < 147456){  // W_ih [1152][128] -> gi
    int row = i>>7, k = i&127;
    int g = row/384, unit = row - g*384, c = unit>>5, lc = unit&31;
    int kf = k>>4, hl = (k>>3)&1, j = k&7;
    stream[(size_t)c*CHU + (size_t)(g*8+kf)*512 + (lc+32*hl)*8 + j] = f2b(Wih[i]);
  }
  if (i < 24576){   // Wd1 [64][384]
    int row = i/384, k = i - row*384;
    int ct = row>>5, lc = row&31;
    int kf = k>>4, hl = (k>>3)&1, j = k&7;
    stream[(size_t)D0_U + (size_t)ct*GI_U + (size_t)kf*512 + (lc+32*hl)*8 + j] = f2b(Wd1[i]);
  }
  if (i < 2048){    // Wd2 padded B-frags [4 kf][512] (n>=3 -> 0)
    int kf = i>>9, r = i&511;
    int n = (r>>3)&31, hl = r>>8, j = r&7;
    int k = kf*16 + hl*8 + j;
    wd2p[i] = f2b((n<3) ? Wd2[n*64 + k] : 0.f);
  }
  if (i < 2048){    // x-MLP B-frags [4 tiles][512]: K=16 (k=0..7 feat, 8..15 zero)
    int tl = i>>9, r = i&511;
    int n = (r>>3)&31, hl = r>>8, j = r&7;
    int k = hl*8 + j, u = tl*32 + n;
    float v = 0.f;
    if      (k <= 2) v = Ws[u*3 + k];
    else if (k == 3) v = bs[u];
    else if (k <= 6) v = Wp[u*3 + (k-4)];
    else if (k == 7) v = bp[u];
    wxp[i] = f2b(v);
  }
  if (i < 384){     // fused gate biases per hidden unit: {r, z, n_i, n_h}
    gb[i*4+0] = bih[i]       + bhh[i];
    gb[i*4+1] = bih[384+i]   + bhh[384+i];
    gb[i*4+2] = bih[768+i];
    gb[i*4+3] = bhh[768+i];
  }
}

// ---------------------------------------------------------------- main ----
__global__ __launch_bounds__(128, 1)
void gru_main(const float* __restrict__ ih, const float* __restrict__ plan,
              const float* __restrict__ gate, const float* __restrict__ istate,
              const u16* __restrict__ stream, const u16* __restrict__ wd2p,
              const u16* __restrict__ wxp, const float* __restrict__ gb,
              const float* __restrict__ bd1, const float* __restrict__ bd2,
              float* __restrict__ out)
{
  __shared__ __attribute__((aligned(16))) u16 wb[2][GH_U];      // 73728 B
  __shared__ __attribute__((aligned(16))) u16 scr[2][32*SS];    //  5120 B (per-wave transpose scratch)
  __shared__ __attribute__((aligned(16))) float sst[2][32][4];  //  1024 B
  // total 79872 B <= 81920 -> 2 blocks/CU

  const int tid  = threadIdx.x;
  const int wave = tid >> 6, lane = tid & 63;
  const int m    = lane & 31, hl = lane >> 5;
  const int R0   = blockIdx.x*64 + wave*32;   // wave's 32 batch rows
  u16* sw = scr[wave];

  const float gt    = gate[R0 + m];
  const float bd1v0 = bd1[m], bd1v1 = bd1[32+m];
  const float bd2v  = (m<3) ? bd2[m] : 0.f;

  if (lane < 32){
    const float* sp = istate + (size_t)(R0+lane)*3;
    sst[wave][lane][0]=sp[0]; sst[wave][lane][1]=sp[1];
    sst[wave][lane][2]=sp[2]; sst[wave][lane][3]=0.f;
  }

  // h lives ONLY in registers: hold = old h (A-frags), hnew = new h.
  u16x8 hold[24], hnew[24];
#pragma unroll
  for (int kf=0; kf<24; ++kf){
    const float* p = ih + (size_t)(R0+m)*384 + kf*16 + hl*8;
    float4 a = *(const float4*)p;
    float4 b = *(const float4*)(p+4);
    u16x8 v;
    v[0]=f2b(a.x); v[1]=f2b(a.y); v[2]=f2b(a.z); v[3]=f2b(a.w);
    v[4]=f2b(b.x); v[5]=f2b(b.y); v[6]=f2b(b.z); v[7]=f2b(b.w);
    hold[kf]=v;
  }

  auto stage24 = [&](int base, int bsel){   // 24 KB phase: each wave stages 12 KB
    const u16* s = stream + base + wave*6144 + lane*8;
    u16* d = &wb[bsel][wave*6144];
#pragma unroll
    for (int ii=0; ii<12; ++ii) stage16(s + ii*512, d + ii*512);
  };
  auto stage36 = [&](int base, int bsel){   // 36 KB phase: each wave stages 18 KB
    const u16* s = stream + base + wave*9216 + lane*8;
    u16* d = &wb[bsel][wave*9216];
#pragma unroll
    for (int ii=0; ii<18; ++ii) stage16(s + ii*512, d + ii*512);
  };

  stage24(0, 0);
  vm_fence(); __syncthreads();
  int buf = 0;

#pragma unroll 1
  for (int t=0; t<TT; ++t){
    // ---- x = (state@Ws^T+bs) + gate*(plan@Wp^T+bp) via padded-K MFMA per tile
    u16x8 a8;
    {
      float4 sv = *(const float4*)&sst[wave][m][0];
      const float* pp = plan + (size_t)(R0+m)*(TT*3) + t*3;
      float f0=sv.x, f1=sv.y, f2=sv.z, f3=1.f;
      float f4=gt*pp[0], f5=gt*pp[1], f6=gt*pp[2], f7=gt;
      if (hl){ a8[0]=0;a8[1]=0;a8[2]=0;a8[3]=0;a8[4]=0;a8[5]=0;a8[6]=0;a8[7]=0; }
      else { a8[0]=f2b(f0);a8[1]=f2b(f1);a8[2]=f2b(f2);a8[3]=f2b(f3);
             a8[4]=f2b(f4);a8[5]=f2b(f5);a8[6]=f2b(f6);a8[7]=f2b(f7); }
    }
    u16x8 xf[8];
#pragma unroll
    for (int tl=0; tl<4; ++tl){
      f32x16 ax;
#pragma unroll
      for (int r=0;r<16;++r) ax[r]=0.f;
      ax = mfma32(a8, *(const u16x8*)(wxp + tl*512 + lane*8), ax);
#pragma unroll
      for (int r=0;r<16;++r){
        int row = (r&3) + ((r>>2)<<3) + 4*hl;
        sw[row*SS + m] = f2b(ax[r]);
      }
      lds_fence();
      xf[2*tl]   = *(const u16x8*)&sw[m*SS + hl*8];
      xf[2*tl+1] = *(const u16x8*)&sw[m*SS + 16 + hl*8];
      lds_fence();
    }

    // ---- 12 chunks x {gi, ghA, ghB+blend}. FULLY UNROLLED: hold[2c]/hnew[2c]
    // must be compile-time register indices (scratch-demotion hazard).
#pragma unroll
    for (int c=0; c<12; ++c){
      f32x16 aR, aZ, aNI, aNH;
      {
        const float4 b4 = *(const float4*)(gb + (size_t)(c*32+m)*4);
#pragma unroll
        for (int r=0;r<16;++r){ aR[r]=b4.x; aZ[r]=b4.y; aNI[r]=b4.z; aNH[r]=b4.w; }
      }
      { // gi: x @ W_ih (3 chains x 8)
        stage36(c*CHU + GI_U, buf^1);
        const u16* W = wb[buf];
#pragma unroll
        for (int kf=0; kf<8; ++kf){
          aR  = mfma32(xf[kf], *(const u16x8*)(W + (kf   )*512 + lane*8), aR);
          aZ  = mfma32(xf[kf], *(const u16x8*)(W + (8+kf )*512 + lane*8), aZ);
          aNI = mfma32(xf[kf], *(const u16x8*)(W + (16+kf)*512 + lane*8), aNI);
        }
        vm_fence(); __syncthreads(); buf^=1;
      }
      { // ghA: h @ W_hh kf0..11 (3 chains x 12)
        stage36(c*CHU + GI_U + GH_U, buf^1);
        const u16* W = wb[buf];
#pragma unroll
        for (int kf=0; kf<12; ++kf){
          u16x8 hA = hold[kf];
          aR  = mfma32(hA, *(const u16x8*)(W + (kf   )*512 + lane*8), aR);
          aZ  = mfma32(hA, *(const u16x8*)(W + (12+kf)*512 + lane*8), aZ);
          aNH = mfma32(hA, *(const u16x8*)(W + (24+kf)*512 + lane*8), aNH);
        }
        vm_fence(); __syncthreads(); buf^=1;
      }
      { // ghB: kf12..23 + GRU elementwise blend via per-wave scratch
        if (c < 11) stage24((c+1)*CHU, buf^1);
        else        stage24(D0_U,      buf^1);
        const u16* W = wb[buf];
#pragma unroll
        for (int kf=0; kf<12; ++kf){
          u16x8 hA = hold[12+kf];
          aR  = mfma32(hA, *(const u16x8*)(W + (kf   )*512 + lane*8), aR);
          aZ  = mfma32(hA, *(const u16x8*)(W + (12+kf)*512 + lane*8), aZ);
          aNH = mfma32(hA, *(const u16x8*)(W + (24+kf)*512 + lane*8), aNH);
        }
        // old h chunk -> scr (A-layout write, constant reg indices)
        *(u16x8*)&sw[m*SS + hl*8]      = hold[2*c];
        *(u16x8*)&sw[m*SS + 16 + hl*8] = hold[2*c+1];
        lds_fence();
#pragma unroll
        for (int r=0;r<16;++r){
          int row = (r&3) + ((r>>2)<<3) + 4*hl;
          float ho = b2f(sw[row*SS + m]);        // old h (C layout)
          float rr = sigf(aR[r]);
          float zz = sigf(aZ[r]);
          float nn = tanh_(aNI[r] + rr*aNH[r]);
          sw[row*SS + m] = f2b((1.f-zz)*nn + zz*ho);  // new h (C layout)
        }
        lds_fence();
        hnew[2*c]   = *(const u16x8*)&sw[m*SS + hl*8];      // new h A-frags
        hnew[2*c+1] = *(const u16x8*)&sw[m*SS + 16 + hl*8];
        vm_fence(); __syncthreads(); buf^=1;
      }
    } // chunks

    // commit new h (register renames/moves, constant indices)
#pragma unroll
    for (int kf=0; kf<24; ++kf) hold[kf] = hnew[kf];

    // ---- decode: d1 = elu(h@Wd1^T + bd1) [2 tiles], then d2 via padded-N MFMA
    f32x16 a0, a1;
#pragma unroll
    for (int r=0;r<16;++r){ a0[r]=bd1v0; a1[r]=bd1v1; }
    { // Wd1 tile 0
      stage24(D1_U, buf^1);
      const u16* W = wb[buf];
#pragma unroll
      for (int kf=0; kf<24; ++kf)
        a0 = mfma32(hold[kf], *(const u16x8*)(W + kf*512 + lane*8), a0);
      vm_fence(); __syncthreads(); buf^=1;
    }
    { // Wd1 tile 1 + epilogue; next stage wraps to chunk0 gi for t+1
      stage24(0, buf^1);
      const u16* W = wb[buf];
#pragma unroll
      for (int kf=0; kf<24; ++kf)
        a1 = mfma32(hold[kf], *(const u16x8*)(W + kf*512 + lane*8), a1);

      u16x8 wd2f0 = *(const u16x8*)(wd2p + 0*512 + lane*8);
      u16x8 wd2f1 = *(const u16x8*)(wd2p + 1*512 + lane*8);
      u16x8 wd2f2 = *(const u16x8*)(wd2p + 2*512 + lane*8);
      u16x8 wd2f3 = *(const u16x8*)(wd2p + 3*512 + lane*8);

      f32x16 ao;
#pragma unroll
      for (int r=0;r<16;++r) ao[r]=0.f;
      // pass 0: d1 units 0..31
#pragma unroll
      for (int r=0;r<16;++r){
        int row = (r&3) + ((r>>2)<<3) + 4*hl;
        float e = a0[r]; e = e>0.f ? e : (__expf(e)-1.f);
        sw[row*SS + m] = f2b(e);
      }
      lds_fence();
      {
        u16x8 af0 = *(const u16x8*)&sw[m*SS + hl*8];
        u16x8 af1 = *(const u16x8*)&sw[m*SS + 16 + hl*8];
        ao = mfma32(af0, wd2f0, ao);
        ao = mfma32(af1, wd2f1, ao);
      }
      lds_fence();
      // pass 1: d1 units 32..63
#pragma unroll
      for (int r=0;r<16;++r){
        int row = (r&3) + ((r>>2)<<3) + 4*hl;
        float e = a1[r]; e = e>0.f ? e : (__expf(e)-1.f);
        sw[row*SS + m] = f2b(e);
      }
      lds_fence();
      {
        u16x8 af0 = *(const u16x8*)&sw[m*SS + hl*8];
        u16x8 af1 = *(const u16x8*)&sw[m*SS + 16 + hl*8];
        ao = mfma32(af0, wd2f2, ao);
        ao = mfma32(af1, wd2f3, ao);
      }

      // out + state update (C cols 0..2 valid)
#pragma unroll
      for (int r=0;r<16;++r){
        int row = (r&3) + ((r>>2)<<3) + 4*hl;
        if (m < 3){
          float ns = sst[wave][row][m] + ao[r] + bd2v;
          out[(size_t)(R0+row)*(TT*3) + t*3 + m] = ns;
          sst[wave][row][m] = ns;
        }
      }
      vm_fence(); __syncthreads(); buf^=1;
    }
  } // t
}

// -------------------------------------------------------------- launch ----
extern "C" void kernel_launch(void* const* d_in, const int* in_sizes, int n_in,
                              void* d_out, int out_size, void* d_ws, size_t ws_size,
                              hipStream_t stream)
{
  (void)in_sizes; (void)n_in; (void)out_size; (void)ws_size;
  const float* ih     = (const float*)d_in[0];
  const float* plan   = (const float*)d_in[1];
  const float* gatep  = (const float*)d_in[2];
  const float* istate = (const float*)d_in[3];
  const float* Wp     = (const float*)d_in[4];
  const float* bp     = (const float*)d_in[5];
  const float* Ws     = (const float*)d_in[6];
  const float* bs     = (const float*)d_in[7];
  const float* Wih    = (const float*)d_in[8];
  const float* bih    = (const float*)d_in[9];
  const float* Whh    = (const float*)d_in[10];
  const float* bhh    = (const float*)d_in[11];
  const float* Wd1    = (const float*)d_in[12];
  const float* bd1    = (const float*)d_in[13];
  const float* Wd2    = (const float*)d_in[14];
  const float* bd2    = (const float*)d_in[15];

  // workspace layout (~1.25 MB)
  u16*   wstream = (u16*)d_ws;                         // 614400 u16 = 1228800 B
  u16*   wd2p    = (u16*)((char*)d_ws + 1228800);      //   2048 u16 =    4096 B
  u16*   wxp     = (u16*)((char*)d_ws + 1232896);      //   2048 u16 =    4096 B
  float* gb      = (float*)((char*)d_ws + 1236992);    //   1536 f32 =    6144 B

  prep_kernel<<<1728, 256, 0, stream>>>(Wih, Whh, Wd1, Wd2, bih, bhh, Ws, bs, Wp, bp,
                                        wstream, wd2p, wxp, gb);
  gru_main<<<512, 128, 0, stream>>>(ih, plan, gatep, istate,
                                    wstream, wd2p, wxp, gb, bd1, bd2, (float*)d_out);
}

// Round 2
// 2014.158 us; speedup vs baseline: 4.5811x; 4.5811x over previous
//
#include <hip/hip_runtime.h>

// Decoder_8014408974552 R6: R4 structure + split accumulator chains.
// R5 POST-MORTEM: keeping old h AND new h in registers (hold[24]+hnew[24] =
// 192 VGPRs) + 64 acc VGPRs forced wholesale demotion of the h arrays to
// scratch -> 4.96 GB hidden HBM fetch, 9227 us. The 2-blocks/CU plan is dead
// on this register/LDS budget. REVERTED to R4's LDS-resident h (hn).
// R6 change vs R4: the gh phases (c*4+1..3) and decode phases were each a
// SINGLE 24-long accumulator-chained MFMA sequence -- issue-bound at MFMA
// dependent latency (~64+ cyc/link), not throughput (32 cyc). Re-associate
// each into 3 interleaved sub-chains of 8 (two transient f32x16 partials,
// merged by VALU at phase end). +32 transient VGPRs, no h-state growth.

#define TT  30
#define NPH 50
#define PHU 12288   // u16 per phase (24576 B)
#define HS  392     // hn row stride in u16 (784 B, 16B-aligned, 0 conflicts)

typedef unsigned short u16;
typedef __bf16 bf16x8 __attribute__((ext_vector_type(8)));
typedef u16    u16x8  __attribute__((ext_vector_type(8)));
typedef float  f32x16 __attribute__((ext_vector_type(16)));

__device__ __forceinline__ u16 f2b(float f){           // fp32 -> bf16 RNE
  unsigned u = __float_as_uint(f);
  u += 0x7FFFu + ((u >> 16) & 1u);
  return (u16)(u >> 16);
}
__device__ __forceinline__ float b2f(u16 h){ return __uint_as_float(((unsigned)h) << 16); }

__device__ __forceinline__ f32x16 mfma32(u16x8 a, u16x8 b, f32x16 c){
  return __builtin_amdgcn_mfma_f32_32x32x16_bf16(
      __builtin_bit_cast(bf16x8, a), __builtin_bit_cast(bf16x8, b), c, 0, 0, 0);
}
__device__ __forceinline__ void lds_fence(){ asm volatile("s_waitcnt lgkmcnt(0)" ::: "memory"); }
__device__ __forceinline__ void vm_fence(){ asm volatile("s_waitcnt vmcnt(0)" ::: "memory"); }
__device__ __forceinline__ float sigf(float x){ return __builtin_amdgcn_rcpf(1.f + __expf(-x)); }
__device__ __forceinline__ float tanh_(float x){ return 2.f*__builtin_amdgcn_rcpf(1.f + __expf(-2.f*x)) - 1.f; }

__device__ __forceinline__ void stage16(const u16* g, u16* l){
  __builtin_amdgcn_global_load_lds(
      (const __attribute__((address_space(1))) unsigned int*)g,
      (__attribute__((address_space(3))) unsigned int*)l, 16, 0, 0);
}

// ---------------------------------------------------------------- prep ----
// Stream layout (50 phases x 24 frags x 1024 B per step):
//   c*4+0 : gi  [gi_r kf0..7][gi_z kf0..7][gi_n kf0..7]   (K=128)
//   c*4+1 : gh_r kf0..23   c*4+2 : gh_z   c*4+3 : gh_n     (K=384)
//   48,49 : Wd1 col-tile 0,1  kf0..23
// frag: u16 idx (lane&31 + 32*(lane>>5))*8 + j -> B[k][n], n=c*32+(lane&31),
// k = kf*16 + (lane>>5)*8 + j
__global__ void prep_kernel(const float* __restrict__ Wih, const float* __restrict__ Whh,
                            const float* __restrict__ Wd1, const float* __restrict__ Wd2,
                            const float* __restrict__ bih, const float* __restrict__ bhh,
                            const float* __restrict__ Ws,  const float* __restrict__ bs,
                            const float* __restrict__ Wp,  const float* __restrict__ bp,
                            u16* __restrict__ stream, u16* __restrict__ wd2p,
                            u16* __restrict__ wxp, float* __restrict__ gb)
{
  int i = blockIdx.x*blockDim.x + threadIdx.x;
  if (i < 442368){  // W_hh [1152][384]
    int row = i/384, k = i - row*384;
    int g = row/384, unit = row - g*384, c = unit>>5, lc = unit&31;
    int kf = k>>4, hl = (k>>3)&1, j = k&7;
    int phase = c*4 + 1 + g;
    stream[(size_t)phase*PHU + kf*512 + (lc+32*hl)*8 + j] = f2b(Whh[i]);
  }
  if (i < 147456){  // W_ih [1152][128]
    int row = i>>7, k = i&127;
    int g = row/384, unit = row - g*384, c = unit>>5, lc = unit&31;
    int kf = k>>4, hl = (k>>3)&1, j = k&7;
    int phase = c*4;
    stream[(size_t)phase*PHU + (g*8+kf)*512 + (lc+32*hl)*8 + j] = f2b(Wih[i]);
  }
  if (i < 24576){   // Wd1 [64][384]
    int row = i/384, k = i - row*384;
    int ct = row>>5, lc = row&31;
    int kf = k>>4, hl = (k>>3)&1, j = k&7;
    int phase = 48 + ct;
    stream[(size_t)phase*PHU + kf*512 + (lc+32*hl)*8 + j] = f2b(Wd1[i]);
  }
  if (i < 2048){    // Wd2 padded B-frags [4 kf][512] (n>=3 -> 0)
    int kf = i>>9, r = i&511;
    int n = (r>>3)&31, hl = r>>8, j = r&7;
    int k = kf*16 + hl*8 + j;
    wd2p[i] = f2b((n<3) ? Wd2[n*64 + k] : 0.f);
  }
  if (i < 2048){    // x-MLP B-frags [4 tiles][512]: K=16 (k=0..7 feat, 8..15 zero)
    int tl = i>>9, r = i&511;
    int n = (r>>3)&31, hl = r>>8, j = r&7;
    int k = hl*8 + j, u = tl*32 + n;
    float v = 0.f;
    if      (k <= 2) v = Ws[u*3 + k];
    else if (k == 3) v = bs[u];
    else if (k <= 6) v = Wp[u*3 + (k-4)];
    else if (k == 7) v = bp[u];
    wxp[i] = f2b(v);
  }
  if (i < 384){     // fused gate biases per hidden unit: {r, z, n_i, n_h}
    gb[i*4+0] = bih[i]       + bhh[i];
    gb[i*4+1] = bih[384+i]   + bhh[384+i];
    gb[i*4+2] = bih[768+i];
    gb[i*4+3] = bhh[768+i];
  }
}

// ---------------------------------------------------------------- main ----
__global__ __launch_bounds__(256, 1)
void gru_main(const float* __restrict__ ih, const float* __restrict__ plan,
              const float* __restrict__ gate, const float* __restrict__ istate,
              const u16* __restrict__ stream, const u16* __restrict__ wd2p,
              const u16* __restrict__ wxp, const float* __restrict__ gb,
              const float* __restrict__ bd1, const float* __restrict__ bd2,
              float* __restrict__ out)
{
  __shared__ __attribute__((aligned(16))) u16 wb[2][PHU];   //  49152 B
  __shared__ __attribute__((aligned(16))) u16 hn[4][32*HS]; // 100352 B (wave-private h)
  __shared__ float sst[4][32][4];                           //   2048 B

  const int tid  = threadIdx.x;
  const int wave = tid >> 6, lane = tid & 63;
  const int m    = lane & 31, hl = lane >> 5;
  const int R0   = blockIdx.x*128 + wave*32;   // wave's 32 batch rows
  u16* hw = hn[wave];

  const float gt    = gate[R0 + m];
  const float bd1v0 = bd1[m], bd1v1 = bd1[32+m];
  const float bd2v  = (m<3) ? bd2[m] : 0.f;

  if (lane < 32){
    const float* sp = istate + (size_t)(R0+lane)*3;
    sst[wave][lane][0]=sp[0]; sst[wave][lane][1]=sp[1];
    sst[wave][lane][2]=sp[2]; sst[wave][lane][3]=0.f;
  }

  // initial hidden -> A-frags AND the persistent LDS h-buffer
  u16x8 hold[24];
#pragma unroll
  for (int kf=0; kf<24; ++kf){
    const float* p = ih + (size_t)(R0+m)*384 + kf*16 + hl*8;
    float4 a = *(const float4*)p;
    float4 b = *(const float4*)(p+4);
    u16x8 v;
    v[0]=f2b(a.x); v[1]=f2b(a.y); v[2]=f2b(a.z); v[3]=f2b(a.w);
    v[4]=f2b(b.x); v[5]=f2b(b.y); v[6]=f2b(b.z); v[7]=f2b(b.w);
    hold[kf]=v;
    *(u16x8*)&hw[m*HS + kf*16 + hl*8] = v;
  }

  const u16* srcb = stream + wave*3072 + lane*8;  // this wave's quarter + lane slot
  auto stage = [&](int ph, int bsel){
    const u16* s = srcb + (size_t)ph*PHU;
    u16* d = &wb[bsel][wave*3072];
#pragma unroll
    for (int ii=0; ii<6; ++ii) stage16(s + ii*512, d + ii*512);
  };

  stage(0, 0);
  vm_fence(); __syncthreads();
  int buf = 0, gp = 0;

#pragma unroll 1
  for (int t=0; t<TT; ++t){
    // ---- x = (state@Ws^T+bs) + gate*(plan@Wp^T+bp) via one padded-K MFMA per tile
    u16x8 a8;
    {
      float4 sv = *(const float4*)&sst[wave][m][0];
      const float* pp = plan + (size_t)(R0+m)*(TT*3) + t*3;
      float f0=sv.x, f1=sv.y, f2=sv.z, f3=1.f;
      float f4=gt*pp[0], f5=gt*pp[1], f6=gt*pp[2], f7=gt;
      if (hl){ a8[0]=0;a8[1]=0;a8[2]=0;a8[3]=0;a8[4]=0;a8[5]=0;a8[6]=0;a8[7]=0; }
      else { a8[0]=f2b(f0);a8[1]=f2b(f1);a8[2]=f2b(f2);a8[3]=f2b(f3);
             a8[4]=f2b(f4);a8[5]=f2b(f5);a8[6]=f2b(f6);a8[7]=f2b(f7); }
    }
    u16x8 xf[8];
#pragma unroll
    for (int tl=0; tl<4; ++tl){
      f32x16 ax;
#pragma unroll
      for (int r=0;r<16;++r) ax[r]=0.f;
      ax = mfma32(a8, *(const u16x8*)(wxp + tl*512 + lane*8), ax);
      // C-layout -> hn chunk-0 slice (scratch) -> A-frags
#pragma unroll
      for (int r=0;r<16;++r){
        int row = (r&3) + ((r>>2)<<3) + 4*hl;
        hw[row*HS + m] = f2b(ax[r]);
      }
      lds_fence();
      xf[2*tl]   = *(const u16x8*)&hw[m*HS + hl*8];
      xf[2*tl+1] = *(const u16x8*)&hw[m*HS + 16 + hl*8];
      lds_fence();
    }
    // restore chunk-0 slice of old h from hold (CONSTANT indices)
    *(u16x8*)&hw[m*HS + hl*8]      = hold[0];
    *(u16x8*)&hw[m*HS + 16 + hl*8] = hold[1];
    lds_fence();

#pragma unroll 1
    for (int c=0; c<12; ++c){
      f32x16 aR, aZ, aNI, aNH;
      {
        const float4 b4 = *(const float4*)(gb + (size_t)(c*32+m)*4);
#pragma unroll
        for (int r=0;r<16;++r){ aR[r]=b4.x; aZ[r]=b4.y; aNI[r]=b4.z; aNH[r]=b4.w; }
      }
      { // phase c*4: gi (r,z,n from x) -- 3 independent chains of 8 already
        int np = gp+1; stage(np, buf^1);
        const u16* W = wb[buf];
#pragma unroll
        for (int kf=0; kf<8; ++kf){
          u16x8 bR = *(const u16x8*)(W + (kf    )*512 + lane*8);
          u16x8 bZ = *(const u16x8*)(W + (8+kf  )*512 + lane*8);
          u16x8 bN = *(const u16x8*)(W + (16+kf )*512 + lane*8);
          aR  = mfma32(xf[kf], bR, aR);
          aZ  = mfma32(xf[kf], bZ, aZ);
          aNI = mfma32(xf[kf], bN, aNI);
        }
        vm_fence(); __syncthreads(); buf^=1; gp=np;
      }
      { // phase c*4+1: gh_r -- split 24-chain into 3 interleaved sub-chains
        int np = gp+1; stage(np, buf^1);
        const u16* W = wb[buf];
        f32x16 p1, p2;
#pragma unroll
        for (int r=0;r<16;++r){ p1[r]=0.f; p2[r]=0.f; }
#pragma unroll
        for (int kf=0; kf<8; ++kf){
          aR = mfma32(hold[3*kf  ], *(const u16x8*)(W + (3*kf  )*512 + lane*8), aR);
          p1 = mfma32(hold[3*kf+1], *(const u16x8*)(W + (3*kf+1)*512 + lane*8), p1);
          p2 = mfma32(hold[3*kf+2], *(const u16x8*)(W + (3*kf+2)*512 + lane*8), p2);
        }
#pragma unroll
        for (int r=0;r<16;++r) aR[r] += p1[r] + p2[r];
        vm_fence(); __syncthreads(); buf^=1; gp=np;
      }
      { // phase c*4+2: gh_z -- split chains
        int np = gp+1; stage(np, buf^1);
        const u16* W = wb[buf];
        f32x16 p1, p2;
#pragma unroll
        for (int r=0;r<16;++r){ p1[r]=0.f; p2[r]=0.f; }
#pragma unroll
        for (int kf=0; kf<8; ++kf){
          aZ = mfma32(hold[3*kf  ], *(const u16x8*)(W + (3*kf  )*512 + lane*8), aZ);
          p1 = mfma32(hold[3*kf+1], *(const u16x8*)(W + (3*kf+1)*512 + lane*8), p1);
          p2 = mfma32(hold[3*kf+2], *(const u16x8*)(W + (3*kf+2)*512 + lane*8), p2);
        }
#pragma unroll
        for (int r=0;r<16;++r) aZ[r] += p1[r] + p2[r];
        vm_fence(); __syncthreads(); buf^=1; gp=np;
      }
      { // phase c*4+3: gh_n (split chains) + GRU elementwise, blended in hn
        int np = gp+1; stage(np, buf^1);
        const u16* W = wb[buf];
        f32x16 p1, p2;
#pragma unroll
        for (int r=0;r<16;++r){ p1[r]=0.f; p2[r]=0.f; }
#pragma unroll
        for (int kf=0; kf<8; ++kf){
          aNH = mfma32(hold[3*kf  ], *(const u16x8*)(W + (3*kf  )*512 + lane*8), aNH);
          p1  = mfma32(hold[3*kf+1], *(const u16x8*)(W + (3*kf+1)*512 + lane*8), p1);
          p2  = mfma32(hold[3*kf+2], *(const u16x8*)(W + (3*kf+2)*512 + lane*8), p2);
        }
#pragma unroll
        for (int r=0;r<16;++r) aNH[r] += p1[r] + p2[r];
#pragma unroll
        for (int r=0;r<16;++r){
          int row = (r&3) + ((r>>2)<<3) + 4*hl;
          float rr = sigf(aR[r]);
          float zz = sigf(aZ[r]);
          float nn = tanh_(aNI[r] + rr*aNH[r]);
          int off = row*HS + c*32 + m;
          float ho = b2f(hw[off]);             // old h
          hw[off] = f2b((1.f-zz)*nn + zz*ho);  // new h, in place
        }
        vm_fence(); __syncthreads(); buf^=1; gp=np;
      }
    } // chunks

    // ---- reload hold[] from hn (full new h for this wave's 32 rows)
    lds_fence();
#pragma unroll
    for (int kf=0; kf<24; ++kf)
      hold[kf] = *(const u16x8*)&hw[m*HS + kf*16 + hl*8];

    // ---- decode: d1 = elu(h@Wd1^T + bd1) [2 tiles], then d2 via padded-N MFMA
    f32x16 a0, a1;
#pragma unroll
    for (int r=0;r<16;++r){ a0[r]=bd1v0; a1[r]=bd1v1; }
    { // phase 48: Wd1 tile 0 -- split chains
      int np = gp+1; stage(np, buf^1);
      const u16* W = wb[buf];
      f32x16 p1, p2;
#pragma unroll
      for (int r=0;r<16;++r){ p1[r]=0.f; p2[r]=0.f; }
#pragma unroll
      for (int kf=0; kf<8; ++kf){
        a0 = mfma32(hold[3*kf  ], *(const u16x8*)(W + (3*kf  )*512 + lane*8), a0);
        p1 = mfma32(hold[3*kf+1], *(const u16x8*)(W + (3*kf+1)*512 + lane*8), p1);
        p2 = mfma32(hold[3*kf+2], *(const u16x8*)(W + (3*kf+2)*512 + lane*8), p2);
      }
#pragma unroll
      for (int r=0;r<16;++r) a0[r] += p1[r] + p2[r];
      vm_fence(); __syncthreads(); buf^=1; gp=np;
    }
    { // phase 49: Wd1 tile 1 (+ epilogue); next stage wraps to phase 0
      int np = (gp+1 == NPH) ? 0 : gp+1;
      stage(np, buf^1);
      const u16* W = wb[buf];
      {
        f32x16 p1, p2;
#pragma unroll
        for (int r=0;r<16;++r){ p1[r]=0.f; p2[r]=0.f; }
#pragma unroll
        for (int kf=0; kf<8; ++kf){
          a1 = mfma32(hold[3*kf  ], *(const u16x8*)(W + (3*kf  )*512 + lane*8), a1);
          p1 = mfma32(hold[3*kf+1], *(const u16x8*)(W + (3*kf+1)*512 + lane*8), p1);
          p2 = mfma32(hold[3*kf+2], *(const u16x8*)(W + (3*kf+2)*512 + lane*8), p2);
        }
#pragma unroll
        for (int r=0;r<16;++r) a1[r] += p1[r] + p2[r];
      }

      // Wd2 frags (short live range, L1-hot)
      u16x8 wd2f0 = *(const u16x8*)(wd2p + 0*512 + lane*8);
      u16x8 wd2f1 = *(const u16x8*)(wd2p + 1*512 + lane*8);
      u16x8 wd2f2 = *(const u16x8*)(wd2p + 2*512 + lane*8);
      u16x8 wd2f3 = *(const u16x8*)(wd2p + 3*512 + lane*8);

      f32x16 ao;
#pragma unroll
      for (int r=0;r<16;++r) ao[r]=0.f;
      // pass 0: d1 units 0..31 (hn chunk-0 slice as scratch)
#pragma unroll
      for (int r=0;r<16;++r){
        int row = (r&3) + ((r>>2)<<3) + 4*hl;
        float e = a0[r]; e = e>0.f ? e : (__expf(e)-1.f);
        hw[row*HS + m] = f2b(e);
      }
      lds_fence();
      {
        u16x8 af0 = *(const u16x8*)&hw[m*HS + hl*8];
        u16x8 af1 = *(const u16x8*)&hw[m*HS + 16 + hl*8];
        ao = mfma32(af0, wd2f0, ao);
        ao = mfma32(af1, wd2f1, ao);
      }
      lds_fence();
      // pass 1: d1 units 32..63
#pragma unroll
      for (int r=0;r<16;++r){
        int row = (r&3) + ((r>>2)<<3) + 4*hl;
        float e = a1[r]; e = e>0.f ? e : (__expf(e)-1.f);
        hw[row*HS + m] = f2b(e);
      }
      lds_fence();
      {
        u16x8 af0 = *(const u16x8*)&hw[m*HS + hl*8];
        u16x8 af1 = *(const u16x8*)&hw[m*HS + 16 + hl*8];
        ao = mfma32(af0, wd2f2, ao);
        ao = mfma32(af1, wd2f3, ao);
      }
      lds_fence();
      // restore chunk-0 slice of NEW h from hold (CONSTANT indices)
      *(u16x8*)&hw[m*HS + hl*8]      = hold[0];
      *(u16x8*)&hw[m*HS + 16 + hl*8] = hold[1];

      // out + state update (C cols 0..2 valid)
#pragma unroll
      for (int r=0;r<16;++r){
        int row = (r&3) + ((r>>2)<<3) + 4*hl;
        if (m < 3){
          float ns = sst[wave][row][m] + ao[r] + bd2v;
          out[(size_t)(R0+row)*(TT*3) + t*3 + m] = ns;
          sst[wave][row][m] = ns;
        }
      }
      vm_fence(); __syncthreads(); buf^=1; gp=np;
    }
  } // t
}

// -------------------------------------------------------------- launch ----
extern "C" void kernel_launch(void* const* d_in, const int* in_sizes, int n_in,
                              void* d_out, int out_size, void* d_ws, size_t ws_size,
                              hipStream_t stream)
{
  (void)in_sizes; (void)n_in; (void)out_size; (void)ws_size;
  const float* ih     = (const float*)d_in[0];
  const float* plan   = (const float*)d_in[1];
  const float* gatep  = (const float*)d_in[2];
  const float* istate = (const float*)d_in[3];
  const float* Wp     = (const float*)d_in[4];
  const float* bp     = (const float*)d_in[5];
  const float* Ws     = (const float*)d_in[6];
  const float* bs     = (const float*)d_in[7];
  const float* Wih    = (const float*)d_in[8];
  const float* bih    = (const float*)d_in[9];
  const float* Whh    = (const float*)d_in[10];
  const float* bhh    = (const float*)d_in[11];
  const float* Wd1    = (const float*)d_in[12];
  const float* bd1    = (const float*)d_in[13];
  const float* Wd2    = (const float*)d_in[14];
  const float* bd2    = (const float*)d_in[15];

  // workspace layout (~1.25 MB)
  u16*   wstream = (u16*)d_ws;                         // 614400 u16 = 1228800 B
  u16*   wd2p    = (u16*)((char*)d_ws + 1228800);      //   2048 u16 =    4096 B
  u16*   wxp     = (u16*)((char*)d_ws + 1232896);      //   2048 u16 =    4096 B
  float* gb      = (float*)((char*)d_ws + 1236992);    //   1536 f32 =    6144 B

  prep_kernel<<<1728, 256, 0, stream>>>(Wih, Whh, Wd1, Wd2, bih, bhh, Ws, bs, Wp, bp,
                                        wstream, wd2p, wxp, gb);
  gru_main<<<256, 256, 0, stream>>>(ih, plan, gatep, istate,
                                    wstream, wd2p, wxp, gb, bd1, bd2, (float*)d_out);
}

// Round 3
// 1950.374 us; speedup vs baseline: 4.7309x; 1.0327x over previous
//
#include <hip/hip_runtime.h>

// Decoder_8014408974552 R7: 8 waves/CU via pair-split chunks.
// R6 POST-MORTEM: chain-splitting hurt (2208 us, MfmaUtil 24.7) -- same-acc
// MFMA chains already issue at throughput (C-operand forwarded). Reverted.
// R4's real limiter: 1 wave/SIMD (Occupancy 11.9%) -> every lgkm wait,
// vmcnt(0) drain and barrier tail is fully exposed; MfmaUtil 29 + VALUBusy 30
// with 0 bank conflicts = idle SIMDs, healthy pipes.
// R7: 512-thread blocks, 8 waves = 4 pairs. A pair shares one 32-row group;
// role 0 computes chunks 0-5, role 1 chunks 6-11 (and decode tile 0/1).
// Same LDS (151552 B, 1 block/CU) but 2 waves/SIMD -> per-wave stalls hide
// behind the co-resident wave. Weight stream re-cut into 50 superphases of
// 24 KB = 12 frags/role; per-gate accumulation order identical to R4.

#define TT  30
#define NHP 50      // superphases per timestep
#define SPU 12288   // u16 per superphase (24576 B = 2 roles x 12 frags x 1KB)
#define RHU 6144    // u16 per role half (12 frags)
#define HS  392     // hn row stride in u16 (784 B, 16B-aligned, 0 conflicts)

typedef unsigned short u16;
typedef __bf16 bf16x8 __attribute__((ext_vector_type(8)));
typedef u16    u16x8  __attribute__((ext_vector_type(8)));
typedef float  f32x16 __attribute__((ext_vector_type(16)));

__device__ __forceinline__ u16 f2b(float f){           // fp32 -> bf16 RNE
  unsigned u = __float_as_uint(f);
  u += 0x7FFFu + ((u >> 16) & 1u);
  return (u16)(u >> 16);
}
__device__ __forceinline__ float b2f(u16 h){ return __uint_as_float(((unsigned)h) << 16); }

__device__ __forceinline__ f32x16 mfma32(u16x8 a, u16x8 b, f32x16 c){
  return __builtin_amdgcn_mfma_f32_32x32x16_bf16(
      __builtin_bit_cast(bf16x8, a), __builtin_bit_cast(bf16x8, b), c, 0, 0, 0);
}
__device__ __forceinline__ void lds_fence(){ asm volatile("s_waitcnt lgkmcnt(0)" ::: "memory"); }
__device__ __forceinline__ void vm_fence(){ asm volatile("s_waitcnt vmcnt(0)" ::: "memory"); }
__device__ __forceinline__ float sigf(float x){ return __builtin_amdgcn_rcpf(1.f + __expf(-x)); }
__device__ __forceinline__ float tanh_(float x){ return 2.f*__builtin_amdgcn_rcpf(1.f + __expf(-2.f*x)) - 1.f; }

__device__ __forceinline__ void stage16(const u16* g, u16* l){
  __builtin_amdgcn_global_load_lds(
      (const __attribute__((address_space(1))) unsigned int*)g,
      (__attribute__((address_space(3))) unsigned int*)l, 16, 0, 0);
}

// ---------------------------------------------------------------- prep ----
// Per-role frag sequence per t (600 frags), role r owns chunks r*6..r*6+5:
//   chunk ci (0..5): base=ci*96
//     gi : q = base + g*8 + kf        (g=0..2 gates r/z/n, kf=0..7,  24 frags)
//     ghX: q = base + 24 + g*24 + kf  (g=0..2, kf=0..23,             72 frags)
//   decode tile r:  q = 576 + kf      (kf=0..23)
// superphase sp=q/12, slot f=q%12; stream u16 offset =
//   sp*SPU + role*RHU + f*512 + (lc+32*hl)*8 + j
__global__ void prep_kernel(const float* __restrict__ Wih, const float* __restrict__ Whh,
                            const float* __restrict__ Wd1, const float* __restrict__ Wd2,
                            const float* __restrict__ bih, const float* __restrict__ bhh,
                            const float* __restrict__ Ws,  const float* __restrict__ bs,
                            const float* __restrict__ Wp,  const float* __restrict__ bp,
                            u16* __restrict__ stream, u16* __restrict__ wd2p,
                            u16* __restrict__ wxp, float* __restrict__ gb)
{
  int i = blockIdx.x*blockDim.x + threadIdx.x;
  if (i < 442368){  // W_hh [1152][384]
    int row = i/384, k = i - row*384;
    int g = row/384, unit = row - g*384, c = unit>>5, lc = unit&31;
    int kf = k>>4, hl = (k>>3)&1, j = k&7;
    int role = c/6, ci = c - role*6;
    int q = ci*96 + 24 + g*24 + kf;
    int sp = q/12, f = q - sp*12;
    stream[(size_t)sp*SPU + role*RHU + f*512 + (lc+32*hl)*8 + j] = f2b(Whh[i]);
  }
  if (i < 147456){  // W_ih [1152][128]
    int row = i>>7, k = i&127;
    int g = row/384, unit = row - g*384, c = unit>>5, lc = unit&31;
    int kf = k>>4, hl = (k>>3)&1, j = k&7;
    int role = c/6, ci = c - role*6;
    int q = ci*96 + g*8 + kf;
    int sp = q/12, f = q - sp*12;
    stream[(size_t)sp*SPU + role*RHU + f*512 + (lc+32*hl)*8 + j] = f2b(Wih[i]);
  }
  if (i < 24576){   // Wd1 [64][384]; tile ct -> role ct
    int row = i/384, k = i - row*384;
    int ct = row>>5, lc = row&31;
    int kf = k>>4, hl = (k>>3)&1, j = k&7;
    int q = 576 + kf;
    int sp = q/12, f = q - sp*12;
    stream[(size_t)sp*SPU + ct*RHU + f*512 + (lc+32*hl)*8 + j] = f2b(Wd1[i]);
  }
  if (i < 2048){    // Wd2 padded B-frags [4 kf][512] (n>=3 -> 0)
    int kf = i>>9, r = i&511;
    int n = (r>>3)&31, hl = r>>8, j = r&7;
    int k = kf*16 + hl*8 + j;
    wd2p[i] = f2b((n<3) ? Wd2[n*64 + k] : 0.f);
  }
  if (i < 2048){    // x-MLP B-frags [4 tiles][512]: K=16 (k=0..7 feat, 8..15 zero)
    int tl = i>>9, r = i&511;
    int n = (r>>3)&31, hl = r>>8, j = r&7;
    int k = hl*8 + j, u = tl*32 + n;
    float v = 0.f;
    if      (k <= 2) v = Ws[u*3 + k];
    else if (k == 3) v = bs[u];
    else if (k <= 6) v = Wp[u*3 + (k-4)];
    else if (k == 7) v = bp[u];
    wxp[i] = f2b(v);
  }
  if (i < 384){     // fused gate biases per hidden unit: {r, z, n_i, n_h}
    gb[i*4+0] = bih[i]       + bhh[i];
    gb[i*4+1] = bih[384+i]   + bhh[384+i];
    gb[i*4+2] = bih[768+i];
    gb[i*4+3] = bhh[768+i];
  }
}

// ---------------------------------------------------------------- main ----
__global__ __launch_bounds__(512, 2)
void gru_main(const float* __restrict__ ih, const float* __restrict__ plan,
              const float* __restrict__ gate, const float* __restrict__ istate,
              const u16* __restrict__ stream, const u16* __restrict__ wd2p,
              const u16* __restrict__ wxp, const float* __restrict__ gb,
              const float* __restrict__ bd1, const float* __restrict__ bd2,
              float* __restrict__ out)
{
  __shared__ __attribute__((aligned(16))) u16 wb[2][SPU];   //  49152 B
  __shared__ __attribute__((aligned(16))) u16 hn[4][32*HS]; // 100352 B (pair-shared h)
  __shared__ float sst[4][32][4];                           //   2048 B
  // total 151552 B -> 1 block/CU, 8 waves = 2 waves/SIMD

  const int tid  = threadIdx.x;
  const int wave = tid >> 6, lane = tid & 63;
  const int pair = wave >> 1, role = wave & 1;
  const int m    = lane & 31, hl = lane >> 5;
  const int R0   = blockIdx.x*128 + pair*32;   // pair's 32 batch rows
  u16* hw = hn[pair];
  const int scol = role*192;                   // role's scratch col base

  const float gt   = gate[R0 + m];
  const float bd1v = bd1[role*32 + m];
  const float bd2v = (m<3) ? bd2[m] : 0.f;

  if (role==0 && lane < 32){
    const float* sp = istate + (size_t)(R0+lane)*3;
    sst[pair][lane][0]=sp[0]; sst[pair][lane][1]=sp[1];
    sst[pair][lane][2]=sp[2]; sst[pair][lane][3]=0.f;
  }

  // initial hidden -> A-frags (both roles); role 0 seeds the LDS h-buffer
  u16x8 hold[24];
#pragma unroll
  for (int kf=0; kf<24; ++kf){
    const float* p = ih + (size_t)(R0+m)*384 + kf*16 + hl*8;
    float4 a = *(const float4*)p;
    float4 b = *(const float4*)(p+4);
    u16x8 v;
    v[0]=f2b(a.x); v[1]=f2b(a.y); v[2]=f2b(a.z); v[3]=f2b(a.w);
    v[4]=f2b(b.x); v[5]=f2b(b.y); v[6]=f2b(b.z); v[7]=f2b(b.w);
    hold[kf]=v;
    if (role==0) *(u16x8*)&hw[m*HS + kf*16 + hl*8] = v;
  }

  const u16* srcb = stream + wave*1536 + lane*8;  // 8 waves x 1536 u16 stripes
  auto stage = [&](int sp, int bsel){
    const u16* s = srcb + (size_t)sp*SPU;
    u16* d = &wb[bsel][wave*1536];
#pragma unroll
    for (int ii=0; ii<3; ++ii) stage16(s + ii*512, d + ii*512);
  };

  stage(0, 0);
  vm_fence(); __syncthreads();
  int buf = 0, gp = 0;

#pragma unroll 1
  for (int t=0; t<TT; ++t){
    // ---- x = (state@Ws^T+bs) + gate*(plan@Wp^T+bp); both roles build full xf
    u16x8 a8;
    {
      float4 sv = *(const float4*)&sst[pair][m][0];
      const float* pp = plan + (size_t)(R0+m)*(TT*3) + t*3;
      float f0=sv.x, f1=sv.y, f2=sv.z, f3=1.f;
      float f4=gt*pp[0], f5=gt*pp[1], f6=gt*pp[2], f7=gt;
      if (hl){ a8[0]=0;a8[1]=0;a8[2]=0;a8[3]=0;a8[4]=0;a8[5]=0;a8[6]=0;a8[7]=0; }
      else { a8[0]=f2b(f0);a8[1]=f2b(f1);a8[2]=f2b(f2);a8[3]=f2b(f3);
             a8[4]=f2b(f4);a8[5]=f2b(f5);a8[6]=f2b(f6);a8[7]=f2b(f7); }
    }
    u16x8 xf[8];
#pragma unroll
    for (int tl=0; tl<4; ++tl){
      f32x16 ax;
#pragma unroll
      for (int r=0;r<16;++r) ax[r]=0.f;
      ax = mfma32(a8, *(const u16x8*)(wxp + tl*512 + lane*8), ax);
      // C-layout -> own scratch slice -> A-frags
#pragma unroll
      for (int r=0;r<16;++r){
        int row = (r&3) + ((r>>2)<<3) + 4*hl;
        hw[row*HS + scol + m] = f2b(ax[r]);
      }
      lds_fence();
      xf[2*tl]   = *(const u16x8*)&hw[m*HS + scol + hl*8];
      xf[2*tl+1] = *(const u16x8*)&hw[m*HS + scol + 16 + hl*8];
      lds_fence();
    }
    // restore own slice with old h (CONSTANT reg indices via role branch)
    if (role==0){
      *(u16x8*)&hw[m*HS + hl*8]       = hold[0];
      *(u16x8*)&hw[m*HS + 16 + hl*8]  = hold[1];
    } else {
      *(u16x8*)&hw[m*HS + 192 + hl*8] = hold[12];
      *(u16x8*)&hw[m*HS + 208 + hl*8] = hold[13];
    }
    lds_fence();

    // ---- 6 chunks x 8 superphases (role's chunks: role*6 + ci)
#pragma unroll 1
    for (int ci=0; ci<6; ++ci){
      const int colb = scol + ci*32;           // this chunk's h columns
      f32x16 aR, aZ, aNI, aNH;
      {
        const float4 b4 = *(const float4*)(gb + (size_t)(colb+m)*4);
#pragma unroll
        for (int r=0;r<16;++r){ aR[r]=b4.x; aZ[r]=b4.y; aNI[r]=b4.z; aNH[r]=b4.w; }
      }
      { // hp0: gi_r kf0..7 (f0..7), gi_z kf0..3 (f8..11)
        int np = gp+1; stage(np, buf^1);
        const u16* W = wb[buf] + role*RHU;
#pragma unroll
        for (int kf=0; kf<8; ++kf)
          aR = mfma32(xf[kf], *(const u16x8*)(W + kf*512 + lane*8), aR);
#pragma unroll
        for (int kf=0; kf<4; ++kf)
          aZ = mfma32(xf[kf], *(const u16x8*)(W + (8+kf)*512 + lane*8), aZ);
        vm_fence(); __syncthreads(); buf^=1; gp=np;
      }
      { // hp1: gi_z kf4..7 (f0..3), gi_n kf0..7 (f4..11)
        int np = gp+1; stage(np, buf^1);
        const u16* W = wb[buf] + role*RHU;
#pragma unroll
        for (int kf=4; kf<8; ++kf)
          aZ = mfma32(xf[kf], *(const u16x8*)(W + (kf-4)*512 + lane*8), aZ);
#pragma unroll
        for (int kf=0; kf<8; ++kf)
          aNI = mfma32(xf[kf], *(const u16x8*)(W + (4+kf)*512 + lane*8), aNI);
        vm_fence(); __syncthreads(); buf^=1; gp=np;
      }
      { // hp2: gh_r kf0..11
        int np = gp+1; stage(np, buf^1);
        const u16* W = wb[buf] + role*RHU;
#pragma unroll
        for (int kf=0; kf<12; ++kf)
          aR = mfma32(hold[kf], *(const u16x8*)(W + kf*512 + lane*8), aR);
        vm_fence(); __syncthreads(); buf^=1; gp=np;
      }
      { // hp3: gh_r kf12..23
        int np = gp+1; stage(np, buf^1);
        const u16* W = wb[buf] + role*RHU;
#pragma unroll
        for (int kk=0; kk<12; ++kk)
          aR = mfma32(hold[12+kk], *(const u16x8*)(W + kk*512 + lane*8), aR);
        vm_fence(); __syncthreads(); buf^=1; gp=np;
      }
      { // hp4: gh_z kf0..11
        int np = gp+1; stage(np, buf^1);
        const u16* W = wb[buf] + role*RHU;
#pragma unroll
        for (int kf=0; kf<12; ++kf)
          aZ = mfma32(hold[kf], *(const u16x8*)(W + kf*512 + lane*8), aZ);
        vm_fence(); __syncthreads(); buf^=1; gp=np;
      }
      { // hp5: gh_z kf12..23
        int np = gp+1; stage(np, buf^1);
        const u16* W = wb[buf] + role*RHU;
#pragma unroll
        for (int kk=0; kk<12; ++kk)
          aZ = mfma32(hold[12+kk], *(const u16x8*)(W + kk*512 + lane*8), aZ);
        vm_fence(); __syncthreads(); buf^=1; gp=np;
      }
      { // hp6: gh_n kf0..11
        int np = gp+1; stage(np, buf^1);
        const u16* W = wb[buf] + role*RHU;
#pragma unroll
        for (int kf=0; kf<12; ++kf)
          aNH = mfma32(hold[kf], *(const u16x8*)(W + kf*512 + lane*8), aNH);
        vm_fence(); __syncthreads(); buf^=1; gp=np;
      }
      { // hp7: gh_n kf12..23 + GRU elementwise blend in place
        int np = gp+1; stage(np, buf^1);
        const u16* W = wb[buf] + role*RHU;
#pragma unroll
        for (int kk=0; kk<12; ++kk)
          aNH = mfma32(hold[12+kk], *(const u16x8*)(W + kk*512 + lane*8), aNH);
#pragma unroll
        for (int r=0;r<16;++r){
          int row = (r&3) + ((r>>2)<<3) + 4*hl;
          float rr = sigf(aR[r]);
          float zz = sigf(aZ[r]);
          float nn = tanh_(aNI[r] + rr*aNH[r]);
          int off = row*HS + colb + m;
          float ho = b2f(hw[off]);             // old h
          hw[off] = f2b((1.f-zz)*nn + zz*ho);  // new h, in place
        }
        vm_fence(); __syncthreads(); buf^=1; gp=np;
      }
    } // chunks

    // ---- reload hold[] (full new h; all blends done before hp47's barrier)
#pragma unroll
    for (int kf=0; kf<24; ++kf)
      hold[kf] = *(const u16x8*)&hw[m*HS + kf*16 + hl*8];

    // ---- decode: this role's Wd1 tile over 2 superphases
    f32x16 a0;
#pragma unroll
    for (int r=0;r<16;++r) a0[r]=bd1v;
    { // hp48: Wd1 tile kf0..11
      int np = gp+1; stage(np, buf^1);
      const u16* W = wb[buf] + role*RHU;
#pragma unroll
      for (int kf=0; kf<12; ++kf)
        a0 = mfma32(hold[kf], *(const u16x8*)(W + kf*512 + lane*8), a0);
      vm_fence(); __syncthreads(); buf^=1; gp=np;
    }
    { // hp49: Wd1 tile kf12..23 + elu into own scratch slice; stage wraps
      int np = (gp+1 == NHP) ? 0 : gp+1;
      stage(np, buf^1);
      const u16* W = wb[buf] + role*RHU;
#pragma unroll
      for (int kk=0; kk<12; ++kk)
        a0 = mfma32(hold[12+kk], *(const u16x8*)(W + kk*512 + lane*8), a0);
#pragma unroll
      for (int r=0;r<16;++r){
        int row = (r&3) + ((r>>2)<<3) + 4*hl;
        float e = a0[r]; e = e>0.f ? e : (__expf(e)-1.f);
        hw[row*HS + scol + m] = f2b(e);
      }
      vm_fence(); __syncthreads(); buf^=1; gp=np;
    }
    // ---- epilogue: d2 from BOTH roles' elu slices
    {
      u16x8 wd2f0 = *(const u16x8*)(wd2p + 0*512 + lane*8);
      u16x8 wd2f1 = *(const u16x8*)(wd2p + 1*512 + lane*8);
      u16x8 wd2f2 = *(const u16x8*)(wd2p + 2*512 + lane*8);
      u16x8 wd2f3 = *(const u16x8*)(wd2p + 3*512 + lane*8);

      u16x8 af0 = *(const u16x8*)&hw[m*HS + hl*8];         // d1 units  0..15
      u16x8 af1 = *(const u16x8*)&hw[m*HS + 16  + hl*8];   //          16..31
      u16x8 af2 = *(const u16x8*)&hw[m*HS + 192 + hl*8];   //          32..47
      u16x8 af3 = *(const u16x8*)&hw[m*HS + 208 + hl*8];   //          48..63
      f32x16 ao;
#pragma unroll
      for (int r=0;r<16;++r) ao[r]=0.f;
      ao = mfma32(af0, wd2f0, ao);
      ao = mfma32(af1, wd2f1, ao);
      ao = mfma32(af2, wd2f2, ao);
      ao = mfma32(af3, wd2f3, ao);

      // all cross-slice reads done before anyone overwrites the slices
      __syncthreads();

      // restore own slice with NEW h (constant reg indices via role branch)
      if (role==0){
        *(u16x8*)&hw[m*HS + hl*8]       = hold[0];
        *(u16x8*)&hw[m*HS + 16 + hl*8]  = hold[1];
      } else {
        *(u16x8*)&hw[m*HS + 192 + hl*8] = hold[12];
        *(u16x8*)&hw[m*HS + 208 + hl*8] = hold[13];
      }

      // out + state update (role 0 writes; C cols 0..2 valid)
      if (role==0){
#pragma unroll
        for (int r=0;r<16;++r){
          int row = (r&3) + ((r>>2)<<3) + 4*hl;
          if (m < 3){
            float ns = sst[pair][row][m] + ao[r] + bd2v;
            out[(size_t)(R0+row)*(TT*3) + t*3 + m] = ns;
            sst[pair][row][m] = ns;
          }
        }
      }
      __syncthreads();   // sst + slice restores visible before next t
    }
  } // t
}

// -------------------------------------------------------------- launch ----
extern "C" void kernel_launch(void* const* d_in, const int* in_sizes, int n_in,
                              void* d_out, int out_size, void* d_ws, size_t ws_size,
                              hipStream_t stream)
{
  (void)in_sizes; (void)n_in; (void)out_size; (void)ws_size;
  const float* ih     = (const float*)d_in[0];
  const float* plan   = (const float*)d_in[1];
  const float* gatep  = (const float*)d_in[2];
  const float* istate = (const float*)d_in[3];
  const float* Wp     = (const float*)d_in[4];
  const float* bp     = (const float*)d_in[5];
  const float* Ws     = (const float*)d_in[6];
  const float* bs     = (const float*)d_in[7];
  const float* Wih    = (const float*)d_in[8];
  const float* bih    = (const float*)d_in[9];
  const float* Whh    = (const float*)d_in[10];
  const float* bhh    = (const float*)d_in[11];
  const float* Wd1    = (const float*)d_in[12];
  const float* bd1    = (const float*)d_in[13];
  const float* Wd2    = (const float*)d_in[14];
  const float* bd2    = (const float*)d_in[15];

  // workspace layout (~1.25 MB)
  u16*   wstream = (u16*)d_ws;                         // 614400 u16 = 1228800 B
  u16*   wd2p    = (u16*)((char*)d_ws + 1228800);      //   2048 u16 =    4096 B
  u16*   wxp     = (u16*)((char*)d_ws + 1232896);      //   2048 u16 =    4096 B
  float* gb      = (float*)((char*)d_ws + 1236992);    //   1536 f32 =    6144 B

  prep_kernel<<<1728, 256, 0, stream>>>(Wih, Whh, Wd1, Wd2, bih, bhh, Ws, bs, Wp, bp,
                                        wstream, wd2p, wxp, gb);
  gru_main<<<256, 512, 0, stream>>>(ih, plan, gatep, istate,
                                    wstream, wd2p, wxp, gb, bd1, bd2, (float*)d_out);
}